// Round 3
// baseline (2366.374 us; speedup 1.0000x reference)
//
#include <hip/hip_runtime.h>
#include <stdint.h>

#define NBLK 256
#define TPB  512
#define SCOPE_AGENT __HIP_MEMORY_SCOPE_AGENT

// ---------------- threefry2x32 (exact JAX semantics) ----------------
__device__ __forceinline__ uint32_t rotl32(uint32_t x, int r) {
  return (x << r) | (x >> (32 - r));
}

__device__ __forceinline__ void tf2x32(uint32_t k0, uint32_t k1,
                                       uint32_t x0, uint32_t x1,
                                       uint32_t& o0, uint32_t& o1) {
  const uint32_t k2 = k0 ^ k1 ^ 0x1BD11BDAu;
#define TFR(r) x0 += x1; x1 = rotl32(x1, (r)); x1 ^= x0;
  x0 += k0; x1 += k1;
  TFR(13) TFR(15) TFR(26) TFR(6)
  x0 += k1; x1 += k2 + 1u;
  TFR(17) TFR(29) TFR(16) TFR(24)
  x0 += k2; x1 += k0 + 2u;
  TFR(13) TFR(15) TFR(26) TFR(6)
  x0 += k0; x1 += k1 + 3u;
  TFR(17) TFR(29) TFR(16) TFR(24)
  x0 += k1; x1 += k2 + 4u;
  TFR(13) TFR(15) TFR(26) TFR(6)
  x0 += k2; x1 += k0 + 5u;
#undef TFR
  o0 = x0; o1 = x1;
}

__device__ __forceinline__ float bits_to_u01(uint32_t b) {
  return __uint_as_float((b >> 9) | 0x3f800000u) - 1.0f;
}

__device__ __forceinline__ float gumbel_from_bits(uint32_t b) {
  float u = bits_to_u01(b);
  u = (u == 0.0f) ? 1.17549435e-38f : u;  // uniform(minval=tiny, maxval=1)
  return -logf(-logf(u));
}

__device__ __forceinline__ float sigf(float x) { return 1.0f / (1.0f + expf(-x)); }

__device__ __forceinline__ float ld_f(const float* p) {
  return __hip_atomic_load(p, __ATOMIC_RELAXED, SCOPE_AGENT);
}
__device__ __forceinline__ void st_f(float* p, float v) {
  __hip_atomic_store(p, v, __ATOMIC_RELAXED, SCOPE_AGENT);
}

// ---------------- sampling for step s (redundant in every wave) ----------
__device__ __forceinline__ void do_sample(
    int s, int l, const float* __restrict__ zl,
    const float (*gum)[16], const float (*uni)[64],
    bool wr, float* __restrict__ dout,
    float& x_l, float& x2_l) {
  // categorical: argmax(gumbel + 2.5*tanh(z/5)), first-index tie rule
  const int j = l & 7;
  float bv; int bi;
  {
    const float a_lo = gum[s][j]     + 2.5f * tanhf(zl[j] / 5.0f);
    const float a_hi = gum[s][j + 8] + 2.5f * tanhf(zl[j + 8] / 5.0f);
    if (a_hi > a_lo) { bv = a_hi; bi = j + 8; } else { bv = a_lo; bi = j; }
  }
#pragma unroll
  for (int d = 1; d < 8; d <<= 1) {
    const float ov = __shfl_xor(bv, d, 64);
    const int   oi = __shfl_xor(bi, d, 64);
    if (ov > bv || (ov == bv && oi < bi)) { bv = ov; bi = oi; }
  }
  const int idx1 = bi;

  // bernoulli head: lane j32 (0..31) owns indices j32 and j32+32
  const int j32 = l & 31;
  const int ci = s >> 1;
  const float cc = (float)ci;
  const float sa = -log1pf(cc * expf(-zl[16 + j32]));
  const float sb = -log1pf(cc * expf(-zl[48 + j32]));
  const float pa = expf(sa);
  const float pb = expf(sb);
  const float blo = ((uni[s][j32] < pa) && (j32 < ci)) ? 1.0f : 0.0f;
  const float bhi = ((uni[s][j32 + 32] < pb) && (j32 + 32 < ci)) ? 1.0f : 0.0f;

  // x[l] = concat(one_hot(idx1,16), t2n(64))[l]; x2 = x[64+l] (l<16)
  const float v1 = __shfl(blo, (l - 16) & 63, 64);
  const float v2 = __shfl(bhi, (l - 48) & 63, 64);
  const float v3 = __shfl(bhi, (l + 16) & 63, 64);
  x_l  = (l < 16) ? ((idx1 == l) ? 1.0f : 0.0f) : ((l < 48) ? v1 : v2);
  x2_l = (l < 16) ? v3 : 0.0f;

  if (wr) {  // block 0 wave 0 writes outputs for step s
    const float lgt = 2.5f * tanhf(zl[l & 15] / 5.0f);
    float mx = lgt;
#pragma unroll
    for (int d = 1; d < 16; d <<= 1) mx = fmaxf(mx, __shfl_xor(mx, d, 64));
    float sm = expf(lgt - mx);
#pragma unroll
    for (int d = 1; d < 16; d <<= 1) sm += __shfl_xor(sm, d, 64);
    const float ls = lgt - mx - logf(sm);
    if (l < 16) {
      dout[s * 16 + l] = ls;                                   // s1
      dout[10240 + s * 16 + l] = (idx1 == l) ? 1.0f : 0.0f;    // t1
    }
    if (l < 32) {
      dout[2048 + s * 64 + l]       = sa;                      // s2 lo
      dout[2048 + s * 64 + 32 + l]  = sb;                      // s2 hi
      dout[12288 + s * 64 + l]      = blo;                     // t2 lo
      dout[12288 + s * 64 + 32 + l] = bhi;                     // t2 hi
    }
  }
}

// ---------------- persistent controller kernel ----------------
// 256 blocks x 512 threads; 1 block/CU -> all blocks co-resident.
// Cross-block data moves via agent-scope atomics (cross-XCD coherent).
__global__ void __launch_bounds__(TPB, 2)
ctrl_kernel(const float* __restrict__ W_ih, const float* __restrict__ W_hh,
            const float* __restrict__ b_ih, const float* __restrict__ b_hh,
            const float* __restrict__ fc1w, const float* __restrict__ fc1b,
            const float* __restrict__ fc2w, const float* __restrict__ fc2b,
            float* __restrict__ dout, void* __restrict__ ws) {
  const int bid = blockIdx.x;
  const int tid = threadIdx.x;
  const int wv = tid >> 6;
  const int l  = tid & 63;

  uint32_t* cnt_h = (uint32_t*)ws;       // [128]
  uint32_t* cnt_z = cnt_h + 128;         // [128]
  float* hbuf = (float*)(cnt_z + 128);   // [2][2048] permuted h
  float* zbuf = hbuf + 4096;             // [80]

  __shared__ float gum[128][16];
  __shared__ float uni[128][64];
  __shared__ __align__(16) float h_lds[2048];
  __shared__ float z_lds[80];
  __shared__ float gbuf[8][4];
  __shared__ double zpd[8];
  __shared__ float c_lds[8];

  // --- RNG tables: JAX threefry PARTITIONABLE mode (modern default) ---
  // split(key,n) foldlike: key_i = tf(key, (0, i)) [full pair]
  // random_bits(key,32,(n,)): bits_i = fold(tf(key, (0, i))) = o0 ^ o1
  if (tid < 8) c_lds[tid] = 0.0f;
  {
    const int s = tid >> 2;   // step 0..127
    const int c = tid & 3;    // chunk 0..3
    uint32_t ka, kb, c0, c1, d0, d1;
    tf2x32(0u, 42u, 0u, (uint32_t)s, ka, kb);   // keys[s]
    tf2x32(ka, kb, 0u, 0u, c0, c1);             // k1 (categorical)
    tf2x32(ka, kb, 0u, 1u, d0, d1);             // k2 (bernoulli uniform)
#pragma unroll
    for (int q = 0; q < 4; ++q) {
      const int j = 4 * c + q;
      uint32_t lo, hi;
      tf2x32(c0, c1, 0u, (uint32_t)j, lo, hi);
      gum[s][j] = gumbel_from_bits(lo ^ hi);
    }
#pragma unroll
    for (int q = 0; q < 16; ++q) {
      const int j = 16 * c + q;
      uint32_t lo, hi;
      tf2x32(d0, d1, 0u, (uint32_t)j, lo, hi);
      uni[s][j] = bits_to_u01(lo ^ hi);
    }
  }

  // --- register-resident W_hh slice: 4 rows x 32 cols per lane ---
  const int g   = wv >> 1;
  const int kb4 = (wv & 1) << 2;
  float4 Wr[4][8];
  float wih_a[4], wih_b[4], bsum[4];
#pragma unroll
  for (int rr = 0; rr < 4; ++rr) {
    const int r = g * 2048 + bid * 8 + kb4 + rr;
    const float* wp = W_hh + (size_t)r * 2048 + 32 * l;
#pragma unroll
    for (int m = 0; m < 8; ++m)
      Wr[rr][m] = *reinterpret_cast<const float4*>(wp + 4 * m);
    wih_a[rr] = W_ih[r * 80 + l];
    wih_b[rr] = (l < 16) ? W_ih[r * 80 + 64 + l] : 0.0f;
    bsum[rr] = b_ih[r] + b_hh[r];
  }
  // head row (permuted to match h_lds layout: pe=4*tid+q <-> e=32*l+4*wv+q)
  float4 fcr = make_float4(0.f, 0.f, 0.f, 0.f);
  float fcb = 0.0f;
  if (bid < 80) {
    const float* fp = (bid < 16) ? (fc1w + (size_t)bid * 2048)
                                 : (fc2w + (size_t)(bid - 16) * 2048);
    fcr = *reinterpret_cast<const float4*>(fp + 32 * l + 4 * wv);
    fcb = (bid < 16) ? fc1b[bid] : fc2b[bid - 16];
  }
  __syncthreads();

  float x_l = 0.0f, x2_l = 0.0f;

#pragma unroll 1
  for (int i = 0; i < 128; ++i) {
    // A: wait for h_i complete (all blocks' step i-1 stores)
    if (i > 0) {
      if (tid == 0) {
        while (__hip_atomic_load(cnt_h + (i - 1), __ATOMIC_RELAXED,
                                 SCOPE_AGENT) < (uint32_t)NBLK)
          __builtin_amdgcn_s_sleep(2);
        __builtin_amdgcn_fence(__ATOMIC_ACQUIRE, "agent");
      }
      __syncthreads();
    }

    // B: stage h_i -> LDS (atomic loads = cross-XCD coherent)
    {
      const int b4 = tid << 2;
      if (i == 0) {
#pragma unroll
        for (int q = 0; q < 4; ++q) h_lds[b4 + q] = 0.0f;
      } else {
        const float* hb = hbuf + ((i & 1) << 11);
#pragma unroll
        for (int q = 0; q < 4; ++q) h_lds[b4 + q] = ld_f(hb + b4 + q);
      }
    }
    __syncthreads();

    // C: head blocks publish z_{i-1} = fc_row . relu(h_i)  (double accum)
    if (i > 0 && bid < 80) {
      const int b4 = tid << 2;
      double dp = 0.0;
      dp = fma((double)fcr.x, (double)fmaxf(h_lds[b4 + 0], 0.0f), dp);
      dp = fma((double)fcr.y, (double)fmaxf(h_lds[b4 + 1], 0.0f), dp);
      dp = fma((double)fcr.z, (double)fmaxf(h_lds[b4 + 2], 0.0f), dp);
      dp = fma((double)fcr.w, (double)fmaxf(h_lds[b4 + 3], 0.0f), dp);
#pragma unroll
      for (int d = 1; d < 64; d <<= 1) dp += __shfl_xor(dp, d, 64);
      if (l == 0) zpd[wv] = dp;
      __syncthreads();
      if (tid == 0) {
        double z = zpd[0];
#pragma unroll
        for (int q = 1; q < 8; ++q) z += zpd[q];
        z += (double)fcb;
        st_f(zbuf + bid, (float)z);
        __hip_atomic_fetch_add(cnt_z + (i - 1), 1u, __ATOMIC_RELEASE,
                               SCOPE_AGENT);
      }
    }

    // D: W_hh @ h_i partial (overlaps the z round on non-head blocks)
    float acc[4] = {0.f, 0.f, 0.f, 0.f};
#pragma unroll
    for (int m = 0; m < 8; ++m) {
      const float4 H = *reinterpret_cast<const float4*>(h_lds + (m << 8) + (l << 2));
#pragma unroll
      for (int rr = 0; rr < 4; ++rr) {
        acc[rr] = fmaf(Wr[rr][m].x, H.x, acc[rr]);
        acc[rr] = fmaf(Wr[rr][m].y, H.y, acc[rr]);
        acc[rr] = fmaf(Wr[rr][m].z, H.z, acc[rr]);
        acc[rr] = fmaf(Wr[rr][m].w, H.w, acc[rr]);
      }
    }

    // E: wait z_{i-1}, stage -> LDS, sample x_i (identical in all blocks)
    if (i > 0) {
      const int s = i - 1;
      if (tid == 0) {
        while (__hip_atomic_load(cnt_z + s, __ATOMIC_RELAXED,
                                 SCOPE_AGENT) < 80u)
          __builtin_amdgcn_s_sleep(2);
        __builtin_amdgcn_fence(__ATOMIC_ACQUIRE, "agent");
      }
      __syncthreads();
      if (tid < 80) z_lds[tid] = ld_f(zbuf + tid);
      __syncthreads();
      do_sample(s, l, z_lds, gum, uni, (bid == 0 && wv == 0), dout, x_l, x2_l);
    }

    // F: fold W_ih@x, reduce, LSTM cell, publish h_{i+1}
#pragma unroll
    for (int rr = 0; rr < 4; ++rr)
      acc[rr] = fmaf(wih_a[rr], x_l, fmaf(wih_b[rr], x2_l, acc[rr]));
#pragma unroll
    for (int rr = 0; rr < 4; ++rr) {
#pragma unroll
      for (int d = 1; d < 64; d <<= 1)
        acc[rr] += __shfl_xor(acc[rr], d, 64);
    }
    if (l == 0) {
#pragma unroll
      for (int rr = 0; rr < 4; ++rr)
        gbuf[wv][rr] = acc[rr] + bsum[rr];
    }
    __syncthreads();
    if (tid < 8) {
      const int t = tid;
      const float gI = gbuf[0 + (t >> 2)][t & 3];
      const float gF = gbuf[2 + (t >> 2)][t & 3];
      const float gG = gbuf[4 + (t >> 2)][t & 3];
      const float gO = gbuf[6 + (t >> 2)][t & 3];
      const float cn = sigf(gF) * c_lds[t] + sigf(gI) * tanhf(gG);
      const float hn = sigf(gO) * tanhf(cn);
      c_lds[t] = cn;
      const int e = (bid << 3) + t;
      const int pe = (((e >> 2) & 7) << 8) + ((e >> 5) << 2) + (e & 3);
      st_f(hbuf + (((i + 1) & 1) << 11) + pe, hn);
    }
    if (tid == 0)
      __hip_atomic_fetch_add(cnt_h + i, 1u, __ATOMIC_RELEASE, SCOPE_AGENT);
  }

  // ---- epilogue: z_127 and outputs for step 127 ----
  if (bid >= 80) return;
  if (tid == 0) {
    while (__hip_atomic_load(cnt_h + 127, __ATOMIC_RELAXED,
                             SCOPE_AGENT) < (uint32_t)NBLK)
      __builtin_amdgcn_s_sleep(2);
    __builtin_amdgcn_fence(__ATOMIC_ACQUIRE, "agent");
  }
  __syncthreads();
  {
    const int b4 = tid << 2;
    const float* hb = hbuf;  // buffer (128&1)=0 holds h_128
#pragma unroll
    for (int q = 0; q < 4; ++q) h_lds[b4 + q] = ld_f(hb + b4 + q);
  }
  __syncthreads();
  {
    const int b4 = tid << 2;
    double dp = 0.0;
    dp = fma((double)fcr.x, (double)fmaxf(h_lds[b4 + 0], 0.0f), dp);
    dp = fma((double)fcr.y, (double)fmaxf(h_lds[b4 + 1], 0.0f), dp);
    dp = fma((double)fcr.z, (double)fmaxf(h_lds[b4 + 2], 0.0f), dp);
    dp = fma((double)fcr.w, (double)fmaxf(h_lds[b4 + 3], 0.0f), dp);
#pragma unroll
    for (int d = 1; d < 64; d <<= 1) dp += __shfl_xor(dp, d, 64);
    if (l == 0) zpd[wv] = dp;
    __syncthreads();
    if (tid == 0) {
      double z = zpd[0];
#pragma unroll
      for (int q = 1; q < 8; ++q) z += zpd[q];
      z += (double)fcb;
      st_f(zbuf + bid, (float)z);
      __hip_atomic_fetch_add(cnt_z + 127, 1u, __ATOMIC_RELEASE, SCOPE_AGENT);
    }
  }
  if (bid != 0) return;
  if (tid == 0) {
    while (__hip_atomic_load(cnt_z + 127, __ATOMIC_RELAXED,
                             SCOPE_AGENT) < 80u)
      __builtin_amdgcn_s_sleep(2);
    __builtin_amdgcn_fence(__ATOMIC_ACQUIRE, "agent");
  }
  __syncthreads();
  if (tid < 80) z_lds[tid] = ld_f(zbuf + tid);
  __syncthreads();
  if (wv == 0) {
    float dxa, dxb;
    do_sample(127, l, z_lds, gum, uni, true, dout, dxa, dxb);
  }
}

extern "C" void kernel_launch(void* const* d_in, const int* in_sizes, int n_in,
                              void* d_out, int out_size, void* d_ws, size_t ws_size,
                              hipStream_t stream) {
  (void)in_sizes; (void)n_in; (void)out_size;
  const size_t need = 1024 + 16384 + 320;  // counters + h(2x) + z
  if (ws_size < need) return;
  const float* W_ih = (const float*)d_in[0];
  const float* W_hh = (const float*)d_in[1];
  const float* b_ih = (const float*)d_in[2];
  const float* b_hh = (const float*)d_in[3];
  const float* fc1w = (const float*)d_in[4];
  const float* fc1b = (const float*)d_in[5];
  const float* fc2w = (const float*)d_in[6];
  const float* fc2b = (const float*)d_in[7];
  hipMemsetAsync(d_ws, 0, need, stream);
  hipLaunchKernelGGL(ctrl_kernel, dim3(NBLK), dim3(TPB), 0, stream,
                     W_ih, W_hh, b_ih, b_hh, fc1w, fc1b, fc2w, fc2b,
                     (float*)d_out, d_ws);
}